// Round 8
// baseline (243.649 us; speedup 1.0000x reference)
//
#include <hip/hip_runtime.h>

#define DEV __device__ __forceinline__

typedef unsigned short u16;
typedef unsigned int u32;
typedef __attribute__((ext_vector_type(8))) short short8;
typedef __attribute__((ext_vector_type(4))) float floatx4;

DEV u16 f2bf(float f) {
  union { float f; unsigned u; } v; v.f = f;
  return (u16)((v.u + 0x7FFFu + ((v.u >> 16) & 1u)) >> 16);  // RNE
}
DEV u32 fbits(float f) { union { float f; u32 u; } v; v.f = f; return v.u; }

DEV void gl2lds16(const void* g, void* l) {
  // async global->LDS, 16B/lane; LDS dest is wave-uniform base + lane*16
  __builtin_amdgcn_global_load_lds((const __attribute__((address_space(1))) void*)g,
                                   (__attribute__((address_space(3))) void*)l, 16, 0, 0);
}

// ---------------- conversions ----------------
__global__ void cvt_f32_bf16_x4(const float* __restrict__ in, u16* __restrict__ out, int n4) {
  int i = blockIdx.x * blockDim.x + threadIdx.x;
  if (i >= n4) return;
  float4 f = ((const float4*)in)[i];
  ushort4 o;
  o.x = f2bf(f.x); o.y = f2bf(f.y); o.z = f2bf(f.z); o.w = f2bf(f.w);
  ((ushort4*)out)[i] = o;
}

// Wt[n*1024+k] = bf16(W[k*1024+n])  (1024x1024)
__global__ void transpose_f32_bf16(const float* __restrict__ W, u16* __restrict__ Wt) {
  __shared__ float t[32][33];
  int tx = threadIdx.x & 31, ty = threadIdx.x >> 5;  // 32x8
  int x0 = blockIdx.x * 32, y0 = blockIdx.y * 32;
#pragma unroll
  for (int i = 0; i < 32; i += 8)
    t[ty + i][tx] = W[(size_t)(y0 + ty + i) * 1024 + x0 + tx];
  __syncthreads();
#pragma unroll
  for (int i = 0; i < 32; i += 8)
    Wt[(size_t)(x0 + ty + i) * 1024 + y0 + tx] = f2bf(t[tx][ty + i]);
}

// ---------------- fused QKV GEMM, BK=64 + global_load_lds + 4 blocks/CU ----------
// (unchanged from round 6)
__global__ __launch_bounds__(256, 4)
void gemm_qkv(const u16* __restrict__ A, const u16* __restrict__ Bt,
              u16* __restrict__ Qo, u16* __restrict__ Ko, u16* __restrict__ Vto,
              float alpha) {
  __shared__ u16 smem[16384];   // 32 KB: As[0..8191], Bs[8192..16383]
  u16* As = smem;
  u16* Bs = smem + 8192;
  const int tid = threadIdx.x;
  const int wave = tid >> 6, lane = tid & 63;
  const int quad = lane >> 4, l16 = lane & 15, l7 = l16 & 7;
  const int n0 = blockIdx.x * 128, m0 = blockIdx.y * 128;
  const int wm = (wave >> 1) * 64, wn = (wave & 1) * 64;

  floatx4 acc[4][4] = {};
  const int sl = lane >> 3;                 // row within 8-row staging group
  const int sp = lane & 7;                  // 16B chunk slot
  for (int kt = 0; kt < 1024; kt += 64) {
    __syncthreads();                        // readers of previous tile done
#pragma unroll
    for (int it = 0; it < 4; ++it) {
      int g = it * 4 + wave;
      int row = g * 8 + sl;
      int lc = (sp ^ (row & 7)) * 8;        // swizzled source chunk
      gl2lds16(&A[(size_t)(m0 + row) * 1024 + kt + lc], &As[g * 512]);
      gl2lds16(&Bt[(size_t)(n0 + row) * 1024 + kt + lc], &Bs[g * 512]);
    }
    __syncthreads();                        // staging visible (vmcnt+lgkm drained)
#pragma unroll
    for (int ks = 0; ks < 2; ++ks) {
      const int rc = ((ks * 4 + quad) ^ l7) * 8;
      short8 ar[4], br[4];
#pragma unroll
      for (int i = 0; i < 4; ++i)
        ar[i] = *(const short8*)&As[(wm + i * 16 + l16) * 64 + rc];
#pragma unroll
      for (int j = 0; j < 4; ++j)
        br[j] = *(const short8*)&Bs[(wn + j * 16 + l16) * 64 + rc];
#pragma unroll
      for (int i = 0; i < 4; ++i)
#pragma unroll
        for (int j = 0; j < 4; ++j)
          acc[i][j] = __builtin_amdgcn_mfma_f32_16x16x32_bf16(ar[i], br[j], acc[i][j], 0, 0, 0);
    }
  }

  if (n0 < 1024) {  // Q, scaled
#pragma unroll
    for (int i = 0; i < 4; ++i) {
      int row = m0 + wm + i * 16 + quad * 4;
#pragma unroll
      for (int j = 0; j < 4; ++j) {
        int col = n0 + wn + j * 16 + l16;
#pragma unroll
        for (int r = 0; r < 4; ++r)
          Qo[(size_t)(row + r) * 1024 + col] = f2bf(acc[i][j][r] * alpha);
      }
    }
  } else if (n0 < 2048) {  // K
#pragma unroll
    for (int i = 0; i < 4; ++i) {
      int row = m0 + wm + i * 16 + quad * 4;
#pragma unroll
      for (int j = 0; j < 4; ++j) {
        int col = n0 - 1024 + wn + j * 16 + l16;
#pragma unroll
        for (int r = 0; r < 4; ++r)
          Ko[(size_t)(row + r) * 1024 + col] = f2bf(acc[i][j][r]);
      }
    }
  } else {  // V -> Vt[((b*16+h)*64+d)*2048 + q] via in-LDS transpose, coalesced stores
    __syncthreads();  // final tile's LDS reads done; reuse all 32 KB
#pragma unroll
    for (int i = 0; i < 4; ++i) {
      int rowrel0 = wm + i * 16 + quad * 4;
#pragma unroll
      for (int j = 0; j < 4; ++j) {
        int colrel = wn + j * 16 + l16;
        ushort4 pk;
        pk.x = f2bf(acc[i][j][0]); pk.y = f2bf(acc[i][j][1]);
        pk.z = f2bf(acc[i][j][2]); pk.w = f2bf(acc[i][j][3]);
        *(ushort4*)&smem[colrel * 128 + (rowrel0 ^ ((colrel & 15) * 8))] = pk;
      }
    }
    __syncthreads();
    const int bb = m0 >> 11, q0r = m0 & 2047;       // 128-tiles never straddle a batch
    const int fl = tid >> 4, qp = (tid & 15) * 8;   // 16 lanes cover one 256 B f-row
#pragma unroll
    for (int p = 0; p < 8; ++p) {
      int f = p * 16 + fl;
      int col = n0 - 2048 + f;
      int h = col >> 6, d = col & 63;
      int sw = (f & 15) * 8;
      uint2 lo = *(const uint2*)&smem[f * 128 + (qp ^ sw)];
      uint2 hi = *(const uint2*)&smem[f * 128 + ((qp + 4) ^ sw)];
      uint4 val = make_uint4(lo.x, lo.y, hi.x, hi.y);
      *(uint4*)&Vto[(size_t)(((bb * 16 + h) * 64 + d)) * 2048 + q0r + qp] = val;
    }
  }
}

// ---------------- output GEMM: out[8192,1024] = ctx x Wo^T + bo (fp32 out) ------
__global__ __launch_bounds__(256, 4)
void gemm_out(const u16* __restrict__ A, const u16* __restrict__ Bt,
              float* __restrict__ C, const float* __restrict__ bias) {
  __shared__ u16 smem[16384];
  u16* As = smem;
  u16* Bs = smem + 8192;
  const int tid = threadIdx.x;
  const int wave = tid >> 6, lane = tid & 63;
  const int quad = lane >> 4, l16 = lane & 15, l7 = l16 & 7;
  const int n0 = blockIdx.x * 128, m0 = blockIdx.y * 128;
  const int wm = (wave >> 1) * 64, wn = (wave & 1) * 64;

  floatx4 acc[4][4] = {};
  const int sl = lane >> 3;
  const int sp = lane & 7;

  for (int kt = 0; kt < 1024; kt += 64) {
    __syncthreads();
#pragma unroll
    for (int it = 0; it < 4; ++it) {
      int g = it * 4 + wave;
      int row = g * 8 + sl;
      int lc = (sp ^ (row & 7)) * 8;
      gl2lds16(&A[(size_t)(m0 + row) * 1024 + kt + lc], &As[g * 512]);
      gl2lds16(&Bt[(size_t)(n0 + row) * 1024 + kt + lc], &Bs[g * 512]);
    }
    __syncthreads();
#pragma unroll
    for (int ks = 0; ks < 2; ++ks) {
      const int rc = ((ks * 4 + quad) ^ l7) * 8;
      short8 ar[4], br[4];
#pragma unroll
      for (int i = 0; i < 4; ++i)
        ar[i] = *(const short8*)&As[(wm + i * 16 + l16) * 64 + rc];
#pragma unroll
      for (int j = 0; j < 4; ++j)
        br[j] = *(const short8*)&Bs[(wn + j * 16 + l16) * 64 + rc];
#pragma unroll
      for (int i = 0; i < 4; ++i)
#pragma unroll
        for (int j = 0; j < 4; ++j)
          acc[i][j] = __builtin_amdgcn_mfma_f32_16x16x32_bf16(ar[i], br[j], acc[i][j], 0, 0, 0);
    }
  }
#pragma unroll
  for (int j = 0; j < 4; ++j) {
    int col = n0 + wn + j * 16 + l16;
    float bj = bias[col];
#pragma unroll
    for (int i = 0; i < 4; ++i) {
      int row = m0 + wm + i * 16 + quad * 4;
#pragma unroll
      for (int r = 0; r < 4; ++r)
        C[(size_t)(row + r) * 1024 + col] = acc[i][j][r] + bj;
    }
  }
}

// ---------------- flash attention (causal), one-barrier K/V pipeline ----------
// Grid 512 XCD-swizzled: s=bx&7, p=(bx>>3)&7, bh=(bx>>6)*8+s (same-bh -> same XCD).
// kv-64 tiles double-buffered: per iter ONE __syncthreads (drains tile-t loads
// that flew behind a full compute phase) -> issue tile t+1 -> compute tile t.
// Q frags live in REGISTERS, loaded once per phase via the Ps scratch region
// (wave w's Q rows == wave w's Ps slice: same-wave in-order DS, no extra barrier).
// LDS 48 KB -> 3 blocks/CU. All rows 64 u16, swizzle chunk ^ (row&7): conflict-free.
__global__ __launch_bounds__(256, 3)
void flash_attn(const u16* __restrict__ Qg, const u16* __restrict__ Kg,
                const u16* __restrict__ Vtg, u16* __restrict__ ctx) {
  __shared__ u16 Ks[2][64 * 64];  // [buf][kv][d]
  __shared__ u16 Vs[2][64 * 64];  // [buf][d][kv]
  __shared__ u16 Ps[4][32 * 64];  // per-wave P^T scratch; also Q staging region
  const int tid = threadIdx.x;
  const int wave = tid >> 6, lane = tid & 63;
  const int quad = lane >> 4, l16 = lane & 15, l7 = l16 & 7;
  const int bx = blockIdx.x;
  const int p = (bx >> 3) & 7;
  const int bh = (bx >> 6) * 8 + (bx & 7);
  const int b = bh >> 4, h = bh & 15;
  const size_t qkbase = (size_t)b * 2048 * 1024 + (size_t)h * 64;
  const size_t vbase = (size_t)bh * 64 * 2048;
  const int sl = lane >> 3, sp = lane & 7;  // staging: 8 lanes x 16B per 64-elem row
  u16* Pw = &Ps[wave][0];
  u16* Qsc = &Ps[0][0];  // 16 KB Q staging scratch (row r lands in Ps[r>>5])

  for (int phase = 0; phase < 2; ++phase) {
    const int qt = phase == 0 ? (15 - p) : p;
    const int q0 = qt * 128;
    const int qbase = q0 + wave * 32;
    const int nt = 2 * qt + 2;  // causal: kv-64 tiles 0..2qt+1

    __syncthreads();  // previous phase's LDS readers done
    {  // issue Q stage (128x64 -> Ps region) and K/V tile 0 -> buf 0
#pragma unroll
      for (int it = 0; it < 4; ++it) {
        int g = it * 4 + wave;
        int r = g * 8 + sl;
        int lc = (sp ^ (r & 7)) * 8;
        gl2lds16(&Qg[qkbase + (size_t)(q0 + r) * 1024 + lc], &Qsc[g * 512]);
      }
#pragma unroll
      for (int it = 0; it < 2; ++it) {
        int g = it * 4 + wave;
        int r = g * 8 + sl;
        int lc = (sp ^ (r & 7)) * 8;
        gl2lds16(&Kg[qkbase + (size_t)r * 1024 + lc], &Ks[0][g * 512]);
        gl2lds16(&Vtg[vbase + (size_t)r * 2048 + lc], &Vs[0][g * 512]);
      }
    }
    __syncthreads();  // Q + tile 0 resident

    // Q fragments -> registers (reads only this wave's Ps slice)
    short8 bq[2][2];
#pragma unroll
    for (int ks = 0; ks < 2; ++ks) {
      const int rc = ((ks * 4 + quad) ^ l7) * 8;
      bq[ks][0] = *(const short8*)&Qsc[(wave * 32 + l16) * 64 + rc];
      bq[ks][1] = *(const short8*)&Qsc[(wave * 32 + 16 + l16) * 64 + rc];
    }

    float lsum[2] = {0.f, 0.f};
    floatx4 o[4][2] = {};  // O^T tiles: [d-frag][q-frag]

    for (int t = 0; t < nt; ++t) {
      const int kv0 = t * 64;
      if (t > 0) __syncthreads();  // tile-t loads drained (flew behind tile t-1 compute)
      if (t + 1 < nt) {            // issue tile t+1 into the other buffer
        const int kvn = kv0 + 64;
        const int bn = (t + 1) & 1;
#pragma unroll
        for (int it = 0; it < 2; ++it) {
          int g = it * 4 + wave;
          int r = g * 8 + sl;
          int lc = (sp ^ (r & 7)) * 8;
          gl2lds16(&Kg[qkbase + (size_t)(kvn + r) * 1024 + lc], &Ks[bn][g * 512]);
          gl2lds16(&Vtg[vbase + (size_t)r * 2048 + kvn + lc], &Vs[bn][g * 512]);
        }
      }
      if (kv0 > qbase + 31) continue;  // fully masked for this wave (no barrier below)

      const u16* Kb = &Ks[t & 1][0];
      const u16* Vb = &Vs[t & 1][0];
      // S^T = K Q^T  (per-wave 64kv x 32q), Q pre-scaled
      floatx4 st[4][2] = {};
#pragma unroll
      for (int ks = 0; ks < 2; ++ks) {
        const int rc = ((ks * 4 + quad) ^ l7) * 8;
#pragma unroll
        for (int mj = 0; mj < 4; ++mj) {
          short8 ak = *(const short8*)&Kb[(mj * 16 + l16) * 64 + rc];
          st[mj][0] = __builtin_amdgcn_mfma_f32_16x16x32_bf16(ak, bq[ks][0], st[mj][0], 0, 0, 0);
          st[mj][1] = __builtin_amdgcn_mfma_f32_16x16x32_bf16(ak, bq[ks][1], st[mj][1], 0, 0, 0);
        }
      }
      // P = exp2(S^T)
#pragma unroll
      for (int mj = 0; mj < 4; ++mj)
#pragma unroll
        for (int qi = 0; qi < 2; ++qi)
#pragma unroll
          for (int r = 0; r < 4; ++r)
            st[mj][qi][r] = __builtin_amdgcn_exp2f(st[mj][qi][r]);
      if (kv0 + 63 > qbase) {  // diagonal region only: causal mask
#pragma unroll
        for (int mj = 0; mj < 4; ++mj)
#pragma unroll
          for (int r = 0; r < 4; ++r) {
            int gk = kv0 + mj * 16 + quad * 4 + r;
#pragma unroll
            for (int qi = 0; qi < 2; ++qi) {
              int gq = qbase + qi * 16 + l16;
              if (gk > gq) st[mj][qi][r] = 0.f;
            }
          }
      }
      // lsum partials
#pragma unroll
      for (int mj = 0; mj < 4; ++mj)
#pragma unroll
        for (int qi = 0; qi < 2; ++qi)
          lsum[qi] += (st[mj][qi][0] + st[mj][qi][1]) + (st[mj][qi][2] + st[mj][qi][3]);
      // pack P^T -> per-wave Ps (truncating bf16 via v_perm; same-wave in-order DS)
#pragma unroll
      for (int qi = 0; qi < 2; ++qi) {
        int rowoff = (qi * 16 + l16) * 64;
#pragma unroll
        for (int mj = 0; mj < 4; ++mj) {
          u32 lo = __builtin_amdgcn_perm(fbits(st[mj][qi][1]), fbits(st[mj][qi][0]), 0x07060302u);
          u32 hi = __builtin_amdgcn_perm(fbits(st[mj][qi][3]), fbits(st[mj][qi][2]), 0x07060302u);
          int off = rowoff + (((mj * 2 + (quad >> 1)) ^ l7) << 3) + (quad & 1) * 4;
          *(uint2*)&Pw[off] = make_uint2(lo, hi);
        }
      }
      // O^T += V^T P^T
#pragma unroll
      for (int ks = 0; ks < 2; ++ks) {
        const int rc = ((ks * 4 + quad) ^ l7) * 8;
        short8 av[4], bp[2];
#pragma unroll
        for (int dj = 0; dj < 4; ++dj)
          av[dj] = *(const short8*)&Vb[(dj * 16 + l16) * 64 + rc];
#pragma unroll
        for (int qi = 0; qi < 2; ++qi)
          bp[qi] = *(const short8*)&Pw[(qi * 16 + l16) * 64 + rc];
#pragma unroll
        for (int dj = 0; dj < 4; ++dj)
#pragma unroll
          for (int qi = 0; qi < 2; ++qi)
            o[dj][qi] = __builtin_amdgcn_mfma_f32_16x16x32_bf16(av[dj], bp[qi], o[dj][qi], 0, 0, 0);
      }
    }
    // epilogue: reduce lsum across quads, normalize, store ctx (8B packed: 4 consecutive d)
#pragma unroll
    for (int qi = 0; qi < 2; ++qi) {
      float tsum = lsum[qi];
      tsum += __shfl_xor(tsum, 16);
      tsum += __shfl_xor(tsum, 32);
      float inv = 1.f / tsum;
      int gq = qbase + qi * 16 + l16;
      size_t rowoff = ((size_t)b * 2048 + gq) * 1024 + (size_t)h * 64 + quad * 4;
#pragma unroll
      for (int dj = 0; dj < 4; ++dj) {
        ushort4 pk;
        pk.x = f2bf(o[dj][qi][0] * inv); pk.y = f2bf(o[dj][qi][1] * inv);
        pk.z = f2bf(o[dj][qi][2] * inv); pk.w = f2bf(o[dj][qi][3] * inv);
        *(ushort4*)&ctx[rowoff + dj * 16] = pk;
      }
    }
  }
}

// ---------------- launch ----------------
extern "C" void kernel_launch(void* const* d_in, const int* in_sizes, int n_in,
                              void* d_out, int out_size, void* d_ws, size_t ws_size,
                              hipStream_t stream) {
  const float* x  = (const float*)d_in[0];
  const float* Wq = (const float*)d_in[1];
  const float* Wk = (const float*)d_in[2];
  const float* Wv = (const float*)d_in[3];
  const float* Wo = (const float*)d_in[4];
  const float* bo = (const float*)d_in[5];
  float* out = (float*)d_out;

  char* ws = (char*)d_ws;
  const size_t MB = (size_t)1 << 20;
  u16* x16    = (u16*)(ws + 0 * MB);    // 16 MB: x bf16 (8192x1024)
  u16* q16    = (u16*)(ws + 16 * MB);   // 16 MB: Q (pre-scaled by sc2)
  u16* k16    = (u16*)(ws + 32 * MB);   // 16 MB: K
  u16* vt16   = (u16*)(ws + 48 * MB);   // 16 MB: V per-head transposed [b,h,d,q]
  u16* c16    = (u16*)(ws + 64 * MB);   // 16 MB: ctx
  u16* wqkvt  = (u16*)(ws + 80 * MB);   // 6 MB: [Wq^T;Wk^T;Wv^T] bf16 (3072x1024)
  u16* wot    = (u16*)(ws + 86 * MB);   // 2 MB: Wo^T bf16

  const float sc2 = 0.125f * 1.44269504089f;  // (1/sqrt(64)) * log2(e)

  cvt_f32_bf16_x4<<<8192, 256, 0, stream>>>(x, x16, 8192 * 1024 / 4);
  dim3 tg(32, 32);
  transpose_f32_bf16<<<tg, 256, 0, stream>>>(Wq, wqkvt);
  transpose_f32_bf16<<<tg, 256, 0, stream>>>(Wk, wqkvt + (size_t)1024 * 1024);
  transpose_f32_bf16<<<tg, 256, 0, stream>>>(Wv, wqkvt + (size_t)2048 * 1024);
  transpose_f32_bf16<<<tg, 256, 0, stream>>>(Wo, wot);

  dim3 g3(3072 / 128, 8192 / 128);  // 24 x 64 = 1536 blocks
  gemm_qkv<<<g3, 256, 0, stream>>>(x16, wqkvt, q16, k16, vt16, sc2);

  flash_attn<<<512, 256, 0, stream>>>(q16, k16, vt16, c16);

  dim3 gO(1024 / 128, 8192 / 128);
  gemm_out<<<gO, 256, 0, stream>>>(c16, wot, out, bo);
}